// Round 6
// baseline (1381.534 us; speedup 1.0000x reference)
//
#include <hip/hip_runtime.h>
#include <hip/hip_bf16.h>
#include <math.h>

#define M_TOTAL 16384   // B*S = 4*4096
#define D_MODEL 1024
#define N_QKV   3072
#define CURV    0.15f
#define EPS_F   1e-6f

typedef __attribute__((ext_vector_type(8))) short short8v;
typedef __attribute__((ext_vector_type(4))) float f32x4;

__device__ __forceinline__ void gl_lds16(const void* g, void* l) {
    __builtin_amdgcn_global_load_lds(
        (const __attribute__((address_space(1))) void*)g,
        (__attribute__((address_space(3))) void*)l, 16, 0, 0);
}
__device__ __forceinline__ unsigned short f2bf_bits(float x) {
    __hip_bfloat16 t = __float2bfloat16(x);
    return *(unsigned short*)&t;
}
__device__ __forceinline__ float bf2f(unsigned short u) {
    return __uint_as_float(((unsigned)u) << 16);
}

// ---------------------------------------------------------------------------
// cast fp32 -> bf16, 4 elems/thread
// ---------------------------------------------------------------------------
__global__ __launch_bounds__(256)
void cast_f32_bf16(const float* __restrict__ in, unsigned short* __restrict__ out,
                   int ngroups)
{
    int i = blockIdx.x * 256 + threadIdx.x;
    if (i >= ngroups) return;
    float4 u = ((const float4*)in)[i];
    ushort4 r;
    r.x = f2bf_bits(u.x); r.y = f2bf_bits(u.y);
    r.z = f2bf_bits(u.z); r.w = f2bf_bits(u.w);
    ((ushort4*)out)[i] = r;
}

// ---------------------------------------------------------------------------
// transpose + cast: W[K][N] fp32  ->  Wt[N][K] bf16.
// ---------------------------------------------------------------------------
__global__ __launch_bounds__(256)
void transpose_cast(const float* __restrict__ W, unsigned short* __restrict__ Wt,
                    int K, int N)
{
    __shared__ float tile[32][33];
    const int n0 = blockIdx.x * 32;
    const int k0 = blockIdx.y * 32;
    const int tx = threadIdx.x & 31;
    const int ty = threadIdx.x >> 5;
    #pragma unroll
    for (int i = 0; i < 32; i += 8)
        tile[ty + i][tx] = W[(size_t)(k0 + ty + i) * N + n0 + tx];
    __syncthreads();
    #pragma unroll
    for (int i = 0; i < 32; i += 8)
        Wt[(size_t)(n0 + ty + i) * K + k0 + tx] = f2bf_bits(tile[tx][ty + i]);
}

// ---------------------------------------------------------------------------
// 256xBN bf16 MFMA GEMM, BK=32, 512 thr = 8 waves (WROWS x 8/WROWS grid).
// Key change vs R5: LDS = 2*(16K + BN*64) bytes (64 KiB at BN=256) -> TWO
// blocks co-resident per CU; barrier drains of one block are filled by the
// other block's waves (m97/m114 mechanism). All MFMAs within a tile hit
// distinct accumulators (BK=32 = one MFMA per acc) -> no dependent-issue
// bubbles. Compiler schedules ds_read<->MFMA with counted lgkmcnt (m97);
// we keep only raw barriers + counted vmcnt(4|3) residency gate.
// XOR swizzle: phys_chunk = k_chunk ^ ((row>>1)&3): conflict-free for the
// stride-64B reads (2 lanes/bank), staged via pre-swizzled source cols.
// ---------------------------------------------------------------------------
template<int BN, int WROWS, int OUT_BF16>
__global__ __launch_bounds__(512, 4)
void gemm_bk32(const unsigned short* __restrict__ A,
               const unsigned short* __restrict__ Bt,
               const float* __restrict__ bias,
               void* __restrict__ Cout,
               int M, int N, int K, int nbx)
{
    constexpr int WCOLS  = 8 / WROWS;
    constexpr int MR     = (256 / WROWS) / 16;
    constexpr int NR     = (BN / WCOLS) / 16;
    constexpr int ABYTES = 256 * 64;            // A region: 256 rows x 32k x 2B
    constexpr int BBYTES = BN * 64;
    constexpr int BUFB   = ABYTES + BBYTES;
    __shared__ __align__(16) char smem[2 * BUFB];

    const int t    = threadIdx.x;
    const int w    = t >> 6;
    const int lane = t & 63;
    const int wm   = w / WCOLS;
    const int wn   = w % WCOLS;
    const int lr   = lane & 15;
    const int hi   = lane >> 4;
    const int physoff = (hi ^ ((lr >> 1) & 3)) << 4;   // swizzled chunk byte off

    // bijective XCD chunk swizzle (gridDim.x % 8 == 0)
    const int nwg  = gridDim.x;
    const int orig = blockIdx.x;
    const int wgid = (orig & 7) * (nwg >> 3) + (orig >> 3);
    const int by = wgid / nbx, bx = wgid % nbx;
    const int bm0 = by * 256, bn0 = bx * BN;

    const int nt = K >> 5;

    // staging source: thread t covers phys chunk t (and t+512 for 256-row
    // regions). chunk i: row=i>>2, phys c'=i&3, logical col = c'^((row>>1)&3).
    const int srow = t >> 2;
    const int scol = (((t & 3) ^ ((srow >> 1) & 3)) << 3);
    const unsigned short* AgT = A  + (size_t)(bm0 + srow) * K + scol;
    const unsigned short* BgT = Bt + (size_t)(bn0 + srow) * K + scol;
    const int wb = w << 10;                     // wave's 1KB slot per gl_lds

    auto STAGE = [&](int tile) {
        const size_t ko = (size_t)tile << 5;
        char* bb = smem + (tile & 1) * BUFB;
        gl_lds16(AgT + ko,                   bb + wb);
        gl_lds16(AgT + ko + (size_t)128 * K, bb + 8192 + wb);
        gl_lds16(BgT + ko,                   bb + ABYTES + wb);
        if (BN == 256)
            gl_lds16(BgT + ko + (size_t)128 * K, bb + ABYTES + 8192 + wb);
    };

    short8v a[MR], b[NR];
    f32x4 acc[MR][NR] = {};

    // ---- prologue: stage tiles 0,1; wait tile 0 resident ----
    STAGE(0); STAGE(1);
    if (BN == 256) asm volatile("s_waitcnt vmcnt(4)" ::: "memory");
    else           asm volatile("s_waitcnt vmcnt(3)" ::: "memory");
    __builtin_amdgcn_s_barrier();

    for (int T = 0; T < nt; ++T) {
        char* base = smem + (T & 1) * BUFB;
        #pragma unroll
        for (int m = 0; m < MR; ++m)
            a[m] = *(const short8v*)(base + ((wm * (MR * 16) + m * 16 + lr) << 6)
                                          + physoff);
        #pragma unroll
        for (int n = 0; n < NR; ++n)
            b[n] = *(const short8v*)(base + ABYTES
                                          + ((wn * (NR * 16) + n * 16 + lr) << 6)
                                          + physoff);
        __builtin_amdgcn_s_setprio(1);
        #pragma unroll
        for (int n = 0; n < NR; ++n)
            #pragma unroll
            for (int m = 0; m < MR; ++m)
                acc[m][n] = __builtin_amdgcn_mfma_f32_16x16x32_bf16(
                                a[m], b[n], acc[m][n], 0, 0, 0);
        __builtin_amdgcn_s_setprio(0);
        __builtin_amdgcn_s_barrier();          // all waves' reads of buf retired
        if (T + 2 < nt) {
            STAGE(T + 2);                      // overwrite just-consumed buf
            if (BN == 256) asm volatile("s_waitcnt vmcnt(4)" ::: "memory");
            else           asm volatile("s_waitcnt vmcnt(3)" ::: "memory");
        } else {
            asm volatile("s_waitcnt vmcnt(0)" ::: "memory");
        }
        __builtin_amdgcn_s_barrier();          // tile T+1 resident for all
    }

    // ---- epilogue: C/D layout col=lane&15, row=hi*4+j ----
    const int r0 = bm0 + wm * (MR * 16) + hi * 4;
    const int cb = bn0 + wn * (NR * 16) + lr;
    float bv[NR];
    #pragma unroll
    for (int n = 0; n < NR; ++n) bv[n] = bias[cb + n * 16];
    if (OUT_BF16) {
        unsigned short* Cb = (unsigned short*)Cout;
        #pragma unroll
        for (int m = 0; m < MR; ++m)
            #pragma unroll
            for (int j = 0; j < 4; ++j) {
                unsigned short* rp = Cb + (size_t)(r0 + m * 16 + j) * N;
                #pragma unroll
                for (int n = 0; n < NR; ++n)
                    rp[cb + n * 16] = f2bf_bits(acc[m][n][j] + bv[n]);
            }
    } else {
        float* Cf = (float*)Cout;
        #pragma unroll
        for (int m = 0; m < MR; ++m)
            #pragma unroll
            for (int j = 0; j < 4; ++j) {
                float* rp = Cf + (size_t)(r0 + m * 16 + j) * N;
                #pragma unroll
                for (int n = 0; n < NR; ++n)
                    rp[cb + n * 16] = acc[m][n][j] + bv[n];
            }
    }
}

// ---------------------------------------------------------------------------
// Per-position head attention (bf16 in, bf16 out). One block per position.
// qkv row layout: [3][16][64]. thread t = (h,g) pair. fp32 internal math.
// ---------------------------------------------------------------------------
__global__ __launch_bounds__(256)
void attn_heads_kernel(const unsigned short* __restrict__ qkv,
                       unsigned short* __restrict__ aout)
{
    __shared__ float qs[16][68], ks[16][68], vs[16][68];
    __shared__ float qsq[16], ksq[16];
    __shared__ float attn_s[16][17];

    const int p = blockIdx.x;
    const int t = threadIdx.x;
    const short8v* rowv = (const short8v*)(qkv + (size_t)p * N_QKV);

    // stage+convert: 384 chunks of 8 bf16
    for (int c = t; c < N_QKV / 8; c += 256) {
        short8v v = rowv[c];
        int e0  = c << 3;
        int sec = e0 >> 10;
        int h   = (e0 >> 6) & 15;
        int d   = e0 & 63;
        float* dst = (sec == 0) ? &qs[h][d] : (sec == 1) ? &ks[h][d] : &vs[h][d];
        #pragma unroll
        for (int i = 0; i < 8; ++i)
            dst[i] = bf2f((unsigned short)v[i]);
    }
    __syncthreads();

    if (t < 32) {
        int hh = t & 15;
        const float* src = (t < 16) ? qs[hh] : ks[hh];
        float s = 0.f;
        #pragma unroll
        for (int d0 = 0; d0 < 64; d0 += 4) {
            float4 u = *(const float4*)(src + d0);
            s = fmaf(u.x,u.x, fmaf(u.y,u.y, fmaf(u.z,u.z, fmaf(u.w,u.w, s))));
        }
        if (t < 16) qsq[hh] = s; else ksq[hh] = s;
    }

    const int h = t >> 4;
    const int g = t & 15;
    float dot = 0.f;
    {
        const float* qr = qs[h];
        const float* kr = ks[g];
        #pragma unroll
        for (int d0 = 0; d0 < 64; d0 += 4) {
            float4 a = *(const float4*)(qr + d0);
            float4 b = *(const float4*)(kr + d0);
            dot = fmaf(a.x,b.x, fmaf(a.y,b.y, fmaf(a.z,b.z, fmaf(a.w,b.w, dot))));
        }
    }
    __syncthreads();

    float dsq = fmaxf(qsq[h] + ksq[g] - 2.f * dot, 0.f);
    dsq = dsq * (1.f + CURV * cosf(sqrtf(dsq + EPS_F)));
    float force = sqrtf(qsq[h]) * sqrtf(ksq[g]) / (dsq + EPS_F);

    float m = force;
    #pragma unroll
    for (int off = 8; off >= 1; off >>= 1)
        m = fmaxf(m, __shfl_xor(m, off, 16));
    float e = expf(force - m);
    float ssum = e;
    #pragma unroll
    for (int off = 8; off >= 1; off >>= 1)
        ssum += __shfl_xor(ssum, off, 16);
    attn_s[h][g] = e / ssum;
    __syncthreads();

    const int d  = t & 63;
    const int hb = t >> 6;
    float o[4] = {0.f, 0.f, 0.f, 0.f};
    #pragma unroll
    for (int gg = 0; gg < 16; ++gg) {
        float vv = vs[gg][d];
        #pragma unroll
        for (int hh = 0; hh < 4; ++hh)
            o[hh] = fmaf(attn_s[hb + hh*4][gg], vv, o[hh]);
    }
    unsigned short* orow = aout + (size_t)p * D_MODEL;
    #pragma unroll
    for (int hh = 0; hh < 4; ++hh)
        orow[(hb + hh*4) * 64 + d] = f2bf_bits(o[hh]);
}

// ---------------------------------------------------------------------------
extern "C" void kernel_launch(void* const* d_in, const int* in_sizes, int n_in,
                              void* d_out, int out_size, void* d_ws, size_t ws_size,
                              hipStream_t stream)
{
    const float* x     = (const float*)d_in[0];   // 16384 x 1024
    const float* W_qkv = (const float*)d_in[1];   // 1024 x 3072
    const float* b_qkv = (const float*)d_in[2];   // 3072
    const float* W_out = (const float*)d_in[3];   // 1024 x 1024
    const float* b_out = (const float*)d_in[4];   // 1024
    float* out = (float*)d_out;                   // 16384 x 1024

    // workspace: [0,96M) qkv bf16 | [96M,128M) xb/ab bf16 | Wt1 6M | Wt2 2M
    char* ws = (char*)d_ws;
    unsigned short* qkvb = (unsigned short*)ws;
    unsigned short* xb   = (unsigned short*)(ws + (size_t)M_TOTAL * N_QKV * 2);
    unsigned short* ab   = xb;   // alias: xb dead after GEMM1
    unsigned short* Wt1  = (unsigned short*)(ws + (size_t)M_TOTAL * N_QKV * 2
                                                + (size_t)M_TOTAL * D_MODEL * 2);
    unsigned short* Wt2  = Wt1 + (size_t)N_QKV * D_MODEL;

    // 0a) cast x -> bf16
    {
        int ngroups = M_TOTAL * D_MODEL / 4;
        cast_f32_bf16<<<ngroups / 256, 256, 0, stream>>>(x, xb, ngroups);
    }
    // 0b) transpose+cast weights
    {
        dim3 g(N_QKV / 32, D_MODEL / 32);
        transpose_cast<<<g, 256, 0, stream>>>(W_qkv, Wt1, D_MODEL, N_QKV);
        dim3 g2(D_MODEL / 32, D_MODEL / 32);
        transpose_cast<<<g2, 256, 0, stream>>>(W_out, Wt2, D_MODEL, D_MODEL);
    }

    // 1) qkv = x @ W_qkv + b_qkv  (bf16 out) — 256x256 tile, 768 wg (2/CU)
    {
        int nbx = N_QKV / 256;                 // 12
        int nwg = (M_TOTAL / 256) * nbx;       // 768 (%8==0)
        gemm_bk32<256, 2, 1><<<nwg, 512, 0, stream>>>(xb, Wt1, b_qkv, qkvb,
                                                      M_TOTAL, N_QKV, D_MODEL, nbx);
    }

    // 2) per-position head attention (bf16 -> bf16)
    attn_heads_kernel<<<M_TOTAL, 256, 0, stream>>>(qkvb, ab);

    // 3) out = ab @ W_out + b_out  (fp32 out) — 256x128 tile, 512 wg (2/CU)
    {
        int nbx = D_MODEL / 128;               // 8
        int nwg = (M_TOTAL / 256) * nbx;       // 512 (%8==0)
        gemm_bk32<128, 4, 0><<<nwg, 512, 0, stream>>>(ab, Wt2, b_out, out,
                                                      M_TOTAL, D_MODEL, D_MODEL, nbx);
    }
}

// Round 7
// 251.779 us; speedup vs baseline: 5.4871x; 5.4871x over previous
//
#include <hip/hip_runtime.h>
#include <hip/hip_bf16.h>
#include <math.h>

#define M_TOTAL 16384   // B*S = 4*4096
#define D_MODEL 1024
#define N_QKV   3072
#define CURV    0.15f
#define EPS_F   1e-6f

typedef __attribute__((ext_vector_type(8))) short short8v;
typedef __attribute__((ext_vector_type(4))) float f32x4;

__device__ __forceinline__ void gl_lds16(const void* g, void* l) {
    __builtin_amdgcn_global_load_lds(
        (const __attribute__((address_space(1))) void*)g,
        (__attribute__((address_space(3))) void*)l, 16, 0, 0);
}
__device__ __forceinline__ unsigned short f2bf_bits(float x) {
    __hip_bfloat16 t = __float2bfloat16(x);
    return *(unsigned short*)&t;
}
__device__ __forceinline__ float bf2f(unsigned short u) {
    return __uint_as_float(((unsigned)u) << 16);
}

// ---------------------------------------------------------------------------
// cast fp32 -> bf16, 4 elems/thread
// ---------------------------------------------------------------------------
__global__ __launch_bounds__(256)
void cast_f32_bf16(const float* __restrict__ in, unsigned short* __restrict__ out,
                   int ngroups)
{
    int i = blockIdx.x * 256 + threadIdx.x;
    if (i >= ngroups) return;
    float4 u = ((const float4*)in)[i];
    ushort4 r;
    r.x = f2bf_bits(u.x); r.y = f2bf_bits(u.y);
    r.z = f2bf_bits(u.z); r.w = f2bf_bits(u.w);
    ((ushort4*)out)[i] = r;
}

// ---------------------------------------------------------------------------
// transpose + cast: W[K][N] fp32  ->  Wt[N][K] bf16.
// ---------------------------------------------------------------------------
__global__ __launch_bounds__(256)
void transpose_cast(const float* __restrict__ W, unsigned short* __restrict__ Wt,
                    int K, int N)
{
    __shared__ float tile[32][33];
    const int n0 = blockIdx.x * 32;
    const int k0 = blockIdx.y * 32;
    const int tx = threadIdx.x & 31;
    const int ty = threadIdx.x >> 5;
    #pragma unroll
    for (int i = 0; i < 32; i += 8)
        tile[ty + i][tx] = W[(size_t)(k0 + ty + i) * N + n0 + tx];
    __syncthreads();
    #pragma unroll
    for (int i = 0; i < 32; i += 8)
        Wt[(size_t)(n0 + ty + i) * K + k0 + tx] = f2bf_bits(tile[tx][ty + i]);
}

// ---------------------------------------------------------------------------
// 128x128 bf16 MFMA GEMM, BK=32, 256 thr = 4 waves (2x2, 64x64 wave-tile).
// Register-feasible co-residency: acc 64 f32 + frags 32 + addr ~14 < 128
// VGPR -> __launch_bounds__(256,4) gives FOUR blocks/CU (LDS 32KB x4).
// Independent co-resident blocks fill each other's barrier drains (m114);
// all 16 MFMAs/tile hit distinct accs. Simple 2-barrier loop; compiler
// emits counted lgkmcnt for ds_read->MFMA (m97). Conflict-free XOR swizzle
// (phys chunk = k_chunk ^ ((row>>1)&3)) via pre-swizzled source cols.
// vmcnt(4): 4 gl_lds of tile T+2 in flight, tile T+1 resident.
// ---------------------------------------------------------------------------
template<int OUT_BF16>
__global__ __launch_bounds__(256, 4)
void gemm128(const unsigned short* __restrict__ A,
             const unsigned short* __restrict__ Bt,
             const float* __restrict__ bias,
             void* __restrict__ Cout,
             int M, int N, int K, int nbx)
{
    constexpr int BUFB = 16384;              // 8KB A + 8KB B per buffer
    __shared__ __align__(16) char smem[2 * BUFB];

    const int t    = threadIdx.x;
    const int w    = t >> 6;
    const int lane = t & 63;
    const int wm   = w >> 1;                 // 0..1
    const int wn   = w & 1;                  // 0..1
    const int lr   = lane & 15;
    const int hi   = lane >> 4;              // 0..3

    // bijective XCD chunk swizzle (gridDim.x % 8 == 0)
    const int nwg  = gridDim.x;
    const int orig = blockIdx.x;
    const int wgid = (orig & 7) * (nwg >> 3) + (orig >> 3);
    const int by = wgid / nbx, bx = wgid % nbx;
    const int bm0 = by * 128, bn0 = bx * 128;

    const int nt = K >> 5;

    // staging: region = 512 chunks of 16B; thread t covers chunks t, t+256.
    // chunk c: row=c>>2, phys col c&3, logical col=(c&3)^((row>>1)&3).
    // rows t>>2 and t>>2+64 share the same swizzle ((row>>1)&3 invariant +64).
    const int srow = t >> 2;
    const int scol = ((t & 3) ^ ((t >> 3) & 3)) << 3;   // element offset
    const unsigned short* Ag = A  + (size_t)(bm0 + srow) * K + scol;
    const unsigned short* Bg = Bt + (size_t)(bn0 + srow) * K + scol;
    const int wb = w << 10;                  // wave-uniform 1KB slot

    auto STAGE = [&](int tile) {
        const size_t ko = (size_t)tile << 5;
        char* bb = smem + (tile & 1) * BUFB;
        gl_lds16(Ag + ko,                  bb + wb);
        gl_lds16(Ag + ko + (size_t)64 * K, bb + 4096 + wb);
        gl_lds16(Bg + ko,                  bb + 8192 + wb);
        gl_lds16(Bg + ko + (size_t)64 * K, bb + 8192 + 4096 + wb);
    };

    short8v a[4], b[4];
    f32x4 acc[4][4] = {};

    // ---- prologue: stage tiles 0,1; tile 0 resident ----
    STAGE(0); STAGE(1);
    asm volatile("s_waitcnt vmcnt(4)" ::: "memory");
    __builtin_amdgcn_s_barrier();

    for (int T = 0; T < nt; ++T) {
        char* base = smem + (T & 1) * BUFB;
        #pragma unroll
        for (int m = 0; m < 4; ++m) {
            const int row = wm * 64 + m * 16 + lr;
            a[m] = *(const short8v*)(base + row * 64
                                     + ((hi ^ ((row >> 1) & 3)) << 4));
        }
        #pragma unroll
        for (int n = 0; n < 4; ++n) {
            const int row = wn * 64 + n * 16 + lr;
            b[n] = *(const short8v*)(base + 8192 + row * 64
                                     + ((hi ^ ((row >> 1) & 3)) << 4));
        }
        #pragma unroll
        for (int n = 0; n < 4; ++n)
            #pragma unroll
            for (int m = 0; m < 4; ++m)
                acc[m][n] = __builtin_amdgcn_mfma_f32_16x16x32_bf16(
                                a[m], b[n], acc[m][n], 0, 0, 0);
        __builtin_amdgcn_s_barrier();        // all waves' buf reads retired
        if (T + 2 < nt) {
            STAGE(T + 2);
            asm volatile("s_waitcnt vmcnt(4)" ::: "memory");
        } else {
            asm volatile("s_waitcnt vmcnt(0)" ::: "memory");
        }
        __builtin_amdgcn_s_barrier();        // tile T+1 resident
    }

    // ---- epilogue: C/D layout col=lane&15, row=hi*4+j ----
    const int r0 = bm0 + wm * 64 + hi * 4;
    const int cb = bn0 + wn * 64 + lr;
    float bv[4];
    #pragma unroll
    for (int n = 0; n < 4; ++n) bv[n] = bias[cb + n * 16];
    if (OUT_BF16) {
        unsigned short* Cb = (unsigned short*)Cout;
        #pragma unroll
        for (int m = 0; m < 4; ++m)
            #pragma unroll
            for (int j = 0; j < 4; ++j) {
                unsigned short* rp = Cb + (size_t)(r0 + m * 16 + j) * N;
                #pragma unroll
                for (int n = 0; n < 4; ++n)
                    rp[cb + n * 16] = f2bf_bits(acc[m][n][j] + bv[n]);
            }
    } else {
        float* Cf = (float*)Cout;
        #pragma unroll
        for (int m = 0; m < 4; ++m)
            #pragma unroll
            for (int j = 0; j < 4; ++j) {
                float* rp = Cf + (size_t)(r0 + m * 16 + j) * N;
                #pragma unroll
                for (int n = 0; n < 4; ++n)
                    rp[cb + n * 16] = acc[m][n][j] + bv[n];
            }
    }
}

// ---------------------------------------------------------------------------
// Per-position head attention (bf16 in, bf16 out). One block per position.
// qkv row layout: [3][16][64]. thread t = (h,g) pair. fp32 internal math.
// ---------------------------------------------------------------------------
__global__ __launch_bounds__(256)
void attn_heads_kernel(const unsigned short* __restrict__ qkv,
                       unsigned short* __restrict__ aout)
{
    __shared__ float qs[16][68], ks[16][68], vs[16][68];
    __shared__ float qsq[16], ksq[16];
    __shared__ float attn_s[16][17];

    const int p = blockIdx.x;
    const int t = threadIdx.x;
    const short8v* rowv = (const short8v*)(qkv + (size_t)p * N_QKV);

    // stage+convert: 384 chunks of 8 bf16
    for (int c = t; c < N_QKV / 8; c += 256) {
        short8v v = rowv[c];
        int e0  = c << 3;
        int sec = e0 >> 10;
        int h   = (e0 >> 6) & 15;
        int d   = e0 & 63;
        float* dst = (sec == 0) ? &qs[h][d] : (sec == 1) ? &ks[h][d] : &vs[h][d];
        #pragma unroll
        for (int i = 0; i < 8; ++i)
            dst[i] = bf2f((unsigned short)v[i]);
    }
    __syncthreads();

    if (t < 32) {
        int hh = t & 15;
        const float* src = (t < 16) ? qs[hh] : ks[hh];
        float s = 0.f;
        #pragma unroll
        for (int d0 = 0; d0 < 64; d0 += 4) {
            float4 u = *(const float4*)(src + d0);
            s = fmaf(u.x,u.x, fmaf(u.y,u.y, fmaf(u.z,u.z, fmaf(u.w,u.w, s))));
        }
        if (t < 16) qsq[hh] = s; else ksq[hh] = s;
    }

    const int h = t >> 4;
    const int g = t & 15;
    float dot = 0.f;
    {
        const float* qr = qs[h];
        const float* kr = ks[g];
        #pragma unroll
        for (int d0 = 0; d0 < 64; d0 += 4) {
            float4 a = *(const float4*)(qr + d0);
            float4 b = *(const float4*)(kr + d0);
            dot = fmaf(a.x,b.x, fmaf(a.y,b.y, fmaf(a.z,b.z, fmaf(a.w,b.w, dot))));
        }
    }
    __syncthreads();

    float dsq = fmaxf(qsq[h] + ksq[g] - 2.f * dot, 0.f);
    dsq = dsq * (1.f + CURV * cosf(sqrtf(dsq + EPS_F)));
    float force = sqrtf(qsq[h]) * sqrtf(ksq[g]) / (dsq + EPS_F);

    float m = force;
    #pragma unroll
    for (int off = 8; off >= 1; off >>= 1)
        m = fmaxf(m, __shfl_xor(m, off, 16));
    float e = expf(force - m);
    float ssum = e;
    #pragma unroll
    for (int off = 8; off >= 1; off >>= 1)
        ssum += __shfl_xor(ssum, off, 16);
    attn_s[h][g] = e / ssum;
    __syncthreads();

    const int d  = t & 63;
    const int hb = t >> 6;
    float o[4] = {0.f, 0.f, 0.f, 0.f};
    #pragma unroll
    for (int gg = 0; gg < 16; ++gg) {
        float vv = vs[gg][d];
        #pragma unroll
        for (int hh = 0; hh < 4; ++hh)
            o[hh] = fmaf(attn_s[hb + hh*4][gg], vv, o[hh]);
    }
    unsigned short* orow = aout + (size_t)p * D_MODEL;
    #pragma unroll
    for (int hh = 0; hh < 4; ++hh)
        orow[(hb + hh*4) * 64 + d] = f2bf_bits(o[hh]);
}

// ---------------------------------------------------------------------------
extern "C" void kernel_launch(void* const* d_in, const int* in_sizes, int n_in,
                              void* d_out, int out_size, void* d_ws, size_t ws_size,
                              hipStream_t stream)
{
    const float* x     = (const float*)d_in[0];   // 16384 x 1024
    const float* W_qkv = (const float*)d_in[1];   // 1024 x 3072
    const float* b_qkv = (const float*)d_in[2];   // 3072
    const float* W_out = (const float*)d_in[3];   // 1024 x 1024
    const float* b_out = (const float*)d_in[4];   // 1024
    float* out = (float*)d_out;                   // 16384 x 1024

    // workspace: [0,96M) qkv bf16 | [96M,128M) xb/ab bf16 | Wt1 6M | Wt2 2M
    char* ws = (char*)d_ws;
    unsigned short* qkvb = (unsigned short*)ws;
    unsigned short* xb   = (unsigned short*)(ws + (size_t)M_TOTAL * N_QKV * 2);
    unsigned short* ab   = xb;   // alias: xb dead after GEMM1
    unsigned short* Wt1  = (unsigned short*)(ws + (size_t)M_TOTAL * N_QKV * 2
                                                + (size_t)M_TOTAL * D_MODEL * 2);
    unsigned short* Wt2  = Wt1 + (size_t)N_QKV * D_MODEL;

    // 0a) cast x -> bf16
    {
        int ngroups = M_TOTAL * D_MODEL / 4;
        cast_f32_bf16<<<ngroups / 256, 256, 0, stream>>>(x, xb, ngroups);
    }
    // 0b) transpose+cast weights
    {
        dim3 g(N_QKV / 32, D_MODEL / 32);
        transpose_cast<<<g, 256, 0, stream>>>(W_qkv, Wt1, D_MODEL, N_QKV);
        dim3 g2(D_MODEL / 32, D_MODEL / 32);
        transpose_cast<<<g2, 256, 0, stream>>>(W_out, Wt2, D_MODEL, D_MODEL);
    }

    // 1) qkv = x @ W_qkv + b_qkv  (bf16 out) — 128x128 tile, 3072 wg (4/CU)
    {
        int nbx = N_QKV / 128;                 // 24
        int nwg = (M_TOTAL / 128) * nbx;       // 3072 (%8==0)
        gemm128<1><<<nwg, 256, 0, stream>>>(xb, Wt1, b_qkv, qkvb,
                                            M_TOTAL, N_QKV, D_MODEL, nbx);
    }

    // 2) per-position head attention (bf16 -> bf16)
    attn_heads_kernel<<<M_TOTAL, 256, 0, stream>>>(qkvb, ab);

    // 3) out = ab @ W_out + b_out  (fp32 out) — 128x128 tile, 1024 wg (4/CU)
    {
        int nbx = D_MODEL / 128;               // 8
        int nwg = (M_TOTAL / 128) * nbx;       // 1024 (%8==0)
        gemm128<0><<<nwg, 256, 0, stream>>>(ab, Wt2, b_out, out,
                                            M_TOTAL, D_MODEL, D_MODEL, nbx);
    }
}